// Round 2
// baseline (191.571 us; speedup 1.0000x reference)
//
#include <hip/hip_runtime.h>
#include <math.h>

// Problem constants (fixed shapes from setup_inputs)
#define B_ 32
#define C_ 192
#define H_ 64
#define W_ 64
#define L_ 4096          // H_*W_
#define L4_ 1024         // L_/4
#define NTHREADS 256
#define PER_THREAD 16    // L_ / NTHREADS
#define CSPLIT 64        // channels per variant (3 variants x 64 = 192)

typedef float  f32x4 __attribute__((ext_vector_type(4)));  // clang-native vec4

// ---------------------------------------------------------------------------
// Kernel 1: per-batch stats + keep mask + stable compaction scan.
// UNCHANGED from verified version (absmax == 0) — do not touch numerics.
// ---------------------------------------------------------------------------
__global__ __launch_bounds__(NTHREADS) void stats_scan_kernel(
    const float* __restrict__ delta,  // [B, L]
    int*  __restrict__ src_idx,       // [B, L] out: src token for dest slot d
    int*  __restrict__ counts,        // [B]
    float* __restrict__ thetas)       // [B]
{
  const int b = blockIdx.x;
  const int t = threadIdx.x;
  const int lane = t & 63;
  const int wid  = t >> 6;            // 4 waves of 64

  __shared__ float  smin[4], smax[4];
  __shared__ float  s_lo, s_rng, s_theta;
  __shared__ double dsum[4], dsum2[4];
  __shared__ int    wsum[4];

  const float* dp = delta + (size_t)b * L_;

  float a[PER_THREAD];
  const float4* d4 = (const float4*)dp;
  #pragma unroll
  for (int i = 0; i < 4; ++i) {
    float4 v = d4[t * 4 + i];
    a[i*4+0] = fabsf(v.x); a[i*4+1] = fabsf(v.y);
    a[i*4+2] = fabsf(v.z); a[i*4+3] = fabsf(v.w);
  }

  // ---- min/max reduce (f32, exact) ----
  float lmin = a[0], lmax = a[0];
  #pragma unroll
  for (int i = 1; i < PER_THREAD; ++i) {
    lmin = fminf(lmin, a[i]);
    lmax = fmaxf(lmax, a[i]);
  }
  #pragma unroll
  for (int off = 32; off; off >>= 1) {
    lmin = fminf(lmin, __shfl_down(lmin, off, 64));
    lmax = fmaxf(lmax, __shfl_down(lmax, off, 64));
  }
  if (lane == 0) { smin[wid] = lmin; smax[wid] = lmax; }
  __syncthreads();
  if (t == 0) {
    float lo = fminf(fminf(smin[0], smin[1]), fminf(smin[2], smin[3]));
    float hi = fmaxf(fmaxf(smax[0], smax[1]), fmaxf(smax[2], smax[3]));
    s_lo  = lo;
    s_rng = fmaxf(hi - lo, 1e-3f);   // clamp_min(0.001), f32 like reference
  }
  __syncthreads();
  const float lo  = s_lo;
  const float rng = s_rng;

  double s = 0.0, s2 = 0.0;
  #pragma unroll
  for (int i = 0; i < PER_THREAD; ++i) {
    float imp = (a[i] - lo) / rng;   // f32 IEEE div, matches reference
    a[i] = imp;
    s  += (double)imp;
    s2 += (double)imp * (double)imp;
  }
  #pragma unroll
  for (int off = 32; off; off >>= 1) {
    s  += __shfl_down(s,  off, 64);
    s2 += __shfl_down(s2, off, 64);
  }
  if (lane == 0) { dsum[wid] = s; dsum2[wid] = s2; }
  __syncthreads();
  if (t == 0) {
    double S  = dsum[0]  + dsum[1]  + dsum[2]  + dsum[3];
    double S2 = dsum2[0] + dsum2[1] + dsum2[2] + dsum2[3];
    double mu  = S / (double)L_;
    double var = (S2 - S * S / (double)L_) / (double)(L_ - 1);  // ddof=1
    if (var < 0.0) var = 0.0;
    double sigma = sqrt(var);
    s_theta = (float)(mu - 0.1 * sigma);
  }
  __syncthreads();
  const float theta = s_theta;

  int flags = 0, cnt = 0;
  #pragma unroll
  for (int i = 0; i < PER_THREAD; ++i) {
    int k = (a[i] >= theta) ? 1 : 0;
    cnt += k;
    flags |= (k << i);
  }
  int inc = cnt;
  #pragma unroll
  for (int off = 1; off < 64; off <<= 1) {
    int y = __shfl_up(inc, off, 64);
    if (lane >= off) inc += y;
  }
  if (lane == 63) wsum[wid] = inc;
  __syncthreads();
  int base = inc - cnt;                       // exclusive within wave
  #pragma unroll
  for (int w = 0; w < 4; ++w)
    if (w < wid) base += wsum[w];             // add preceding waves

  int* sb = src_idx + (size_t)b * L_;
  int p = base;
  #pragma unroll
  for (int i = 0; i < PER_THREAD; ++i) {
    if ((flags >> i) & 1) { sb[p++] = t * PER_THREAD + i; }
  }
  if (t == NTHREADS - 1) {
    counts[b] = base + cnt;   // total kept
    thetas[b] = theta;
  }
}

// ---------------------------------------------------------------------------
// Kernel 2: row compaction, 3 co-compiled variants for within-bench A/B/C.
//   MODE 0: global_load_lds staging + nontemporal store   (ch 0..63)
//   MODE 1: global_load_lds staging + plain store         (ch 64..127)
//   MODE 2: register staging        + plain store         (ch 128..191)
// One block per (b, c) row; grid = 32*64 = 2048 per variant (8 blocks/CU).
// ---------------------------------------------------------------------------
template <int MODE>
__global__ __launch_bounds__(NTHREADS) void gather_kernel(
    const float* __restrict__ x,        // [B, C, L]
    const int*  __restrict__ src_idx,   // [B, L]
    const int*  __restrict__ counts,    // [B]
    const float* __restrict__ thetas,   // [B]
    float* __restrict__ out,            // [B, C, L]
    float* __restrict__ out_tail,       // 2 floats (only written by MODE 0)
    int c0)                             // channel offset of this variant
{
  __shared__ float row[L_];             // 16 KB

  const int blk = blockIdx.x;
  const int b   = blk / CSPLIT;
  const int c   = c0 + (blk % CSPLIT);
  const int t   = threadIdx.x;

  // ---- folded finalize: variant 0, block 0, wave 0 only ----
  if (MODE == 0 && blk == 0 && t < 64) {
    float cc = (t < B_) ? (float)counts[t] : 0.0f;
    float th = (t < B_) ? thetas[t]        : 0.0f;
    #pragma unroll
    for (int off = 32; off; off >>= 1) {
      cc += __shfl_down(cc, off, 64);
      th += __shfl_down(th, off, 64);
    }
    if (t == 0) {
      out_tail[0] = (cc / (float)B_) / (float)L_;  // keep_ratio
      out_tail[1] = th / (float)B_;                // theta_mean
    }
  }

  const size_t rowbase = ((size_t)b * C_ + (size_t)c) * L_;
  const float* xr = x + rowbase;

  // ---- Phase 1: stage row into LDS ----
  if (MODE == 2) {
    // register round trip (round-0 style)
    const float4* x4 = (const float4*)xr;
    float4* r4 = (float4*)row;
    #pragma unroll
    for (int i = 0; i < 4; ++i) r4[t + NTHREADS * i] = x4[t + NTHREADS * i];
  } else {
    // async direct-to-LDS, 16B/lane: wave w instr k covers bytes
    // [(w*4+k)*1024, +1024) — LDS dest = uniform base + lane*16 (HW rule)
    const int lane = t & 63;
    const int w    = t >> 6;
    #pragma unroll
    for (int k = 0; k < 4; ++k) {
      const int seg = w * 4 + k;                      // 0..15, wave-uniform
      const float* gp = xr + ((size_t)seg * 64 + lane) * 4;
      __builtin_amdgcn_global_load_lds(
          (const __attribute__((address_space(1))) void*)gp,
          (__attribute__((address_space(3))) void*)((char*)row + seg * 1024),
          16, 0, 0);
    }
  }
  __syncthreads();   // drains vmcnt (incl. global_load_lds) + lgkmcnt

  // ---- Phase 2: LDS gather -> coalesced store ----
  const int  cnt = counts[b];
  const int4* s4b = (const int4*)(src_idx + (size_t)b * L_);
  f32x4* o4 = (f32x4*)(out + rowbase);

  #pragma unroll
  for (int i = 0; i < 4; ++i) {
    const int j  = t + NTHREADS * i;    // float4 index in [0, 1024)
    const int d0 = j * 4;
    const int4 s = s4b[j];              // L2-resident after first channel
    f32x4 r;
    r.x = (d0 + 0 < cnt) ? row[s.x & (L_ - 1)] : 0.0f;
    r.y = (d0 + 1 < cnt) ? row[s.y & (L_ - 1)] : 0.0f;
    r.z = (d0 + 2 < cnt) ? row[s.z & (L_ - 1)] : 0.0f;
    r.w = (d0 + 3 < cnt) ? row[s.w & (L_ - 1)] : 0.0f;
    if (MODE == 0) {
      __builtin_nontemporal_store(r, o4 + j);
    } else {
      o4[j] = r;
    }
  }
}

// ---------------------------------------------------------------------------
extern "C" void kernel_launch(void* const* d_in, const int* in_sizes, int n_in,
                              void* d_out, int out_size, void* d_ws, size_t ws_size,
                              hipStream_t stream) {
  const float* x     = (const float*)d_in[0];   // [32,192,64,64]
  const float* delta = (const float*)d_in[1];   // [32,1,64,64]
  float* out = (float*)d_out;                   // y (B*C*L) ++ keep_ratio ++ theta_mean

  // workspace layout (unchanged)
  int*   src_idx = (int*)d_ws;                                   // B*L ints = 512 KB
  int*   counts  = (int*)((char*)d_ws + (size_t)B_ * L_ * 4);    // 32 ints
  float* thetas  = (float*)((char*)d_ws + (size_t)B_ * L_ * 4 + 128);

  const size_t y_elems = (size_t)B_ * C_ * L_;  // 25,165,824
  float* out_tail = out + y_elems;

  stats_scan_kernel<<<B_, NTHREADS, 0, stream>>>(delta, src_idx, counts, thetas);

  const int grid = B_ * CSPLIT;  // 2048 blocks per variant
  gather_kernel<0><<<grid, NTHREADS, 0, stream>>>(x, src_idx, counts, thetas,
                                                  out, out_tail, 0);
  gather_kernel<1><<<grid, NTHREADS, 0, stream>>>(x, src_idx, counts, thetas,
                                                  out, out_tail, CSPLIT);
  gather_kernel<2><<<grid, NTHREADS, 0, stream>>>(x, src_idx, counts, thetas,
                                                  out, out_tail, 2 * CSPLIT);
}

// Round 5
// 190.666 us; speedup vs baseline: 1.0047x; 1.0047x over previous
//
#include <hip/hip_runtime.h>
#include <math.h>

// Problem constants (fixed shapes from setup_inputs)
#define B_ 32
#define C_ 192
#define H_ 64
#define W_ 64
#define L_ 4096          // H_*W_
#define L4_ 1024         // L_/4
#define NTHREADS 256
#define PER_THREAD 16    // L_ / NTHREADS

typedef float  f32x4 __attribute__((ext_vector_type(4)));  // clang-native vec4

// ---------------------------------------------------------------------------
// Kernel 1: per-batch stats + keep mask + stable compaction scan.
// UNCHANGED from verified version (absmax == 0) — do not touch numerics.
// ---------------------------------------------------------------------------
__global__ __launch_bounds__(NTHREADS) void stats_scan_kernel(
    const float* __restrict__ delta,  // [B, L]
    int*  __restrict__ src_idx,       // [B, L] out: src token for dest slot d
    int*  __restrict__ counts,        // [B]
    float* __restrict__ thetas)       // [B]
{
  const int b = blockIdx.x;
  const int t = threadIdx.x;
  const int lane = t & 63;
  const int wid  = t >> 6;            // 4 waves of 64

  __shared__ float  smin[4], smax[4];
  __shared__ float  s_lo, s_rng, s_theta;
  __shared__ double dsum[4], dsum2[4];
  __shared__ int    wsum[4];

  const float* dp = delta + (size_t)b * L_;

  float a[PER_THREAD];
  const float4* d4 = (const float4*)dp;
  #pragma unroll
  for (int i = 0; i < 4; ++i) {
    float4 v = d4[t * 4 + i];
    a[i*4+0] = fabsf(v.x); a[i*4+1] = fabsf(v.y);
    a[i*4+2] = fabsf(v.z); a[i*4+3] = fabsf(v.w);
  }

  // ---- min/max reduce (f32, exact) ----
  float lmin = a[0], lmax = a[0];
  #pragma unroll
  for (int i = 1; i < PER_THREAD; ++i) {
    lmin = fminf(lmin, a[i]);
    lmax = fmaxf(lmax, a[i]);
  }
  #pragma unroll
  for (int off = 32; off; off >>= 1) {
    lmin = fminf(lmin, __shfl_down(lmin, off, 64));
    lmax = fmaxf(lmax, __shfl_down(lmax, off, 64));
  }
  if (lane == 0) { smin[wid] = lmin; smax[wid] = lmax; }
  __syncthreads();
  if (t == 0) {
    float lo = fminf(fminf(smin[0], smin[1]), fminf(smin[2], smin[3]));
    float hi = fmaxf(fmaxf(smax[0], smax[1]), fmaxf(smax[2], smax[3]));
    s_lo  = lo;
    s_rng = fmaxf(hi - lo, 1e-3f);   // clamp_min(0.001), f32 like reference
  }
  __syncthreads();
  const float lo  = s_lo;
  const float rng = s_rng;

  double s = 0.0, s2 = 0.0;
  #pragma unroll
  for (int i = 0; i < PER_THREAD; ++i) {
    float imp = (a[i] - lo) / rng;   // f32 IEEE div, matches reference
    a[i] = imp;
    s  += (double)imp;
    s2 += (double)imp * (double)imp;
  }
  #pragma unroll
  for (int off = 32; off; off >>= 1) {
    s  += __shfl_down(s,  off, 64);
    s2 += __shfl_down(s2, off, 64);
  }
  if (lane == 0) { dsum[wid] = s; dsum2[wid] = s2; }
  __syncthreads();
  if (t == 0) {
    double S  = dsum[0]  + dsum[1]  + dsum[2]  + dsum[3];
    double S2 = dsum2[0] + dsum2[1] + dsum2[2] + dsum2[3];
    double mu  = S / (double)L_;
    double var = (S2 - S * S / (double)L_) / (double)(L_ - 1);  // ddof=1
    if (var < 0.0) var = 0.0;
    double sigma = sqrt(var);
    s_theta = (float)(mu - 0.1 * sigma);
  }
  __syncthreads();
  const float theta = s_theta;

  int flags = 0, cnt = 0;
  #pragma unroll
  for (int i = 0; i < PER_THREAD; ++i) {
    int k = (a[i] >= theta) ? 1 : 0;
    cnt += k;
    flags |= (k << i);
  }
  int inc = cnt;
  #pragma unroll
  for (int off = 1; off < 64; off <<= 1) {
    int y = __shfl_up(inc, off, 64);
    if (lane >= off) inc += y;
  }
  if (lane == 63) wsum[wid] = inc;
  __syncthreads();
  int base = inc - cnt;                       // exclusive within wave
  #pragma unroll
  for (int w = 0; w < 4; ++w)
    if (w < wid) base += wsum[w];             // add preceding waves

  int* sb = src_idx + (size_t)b * L_;
  int p = base;
  #pragma unroll
  for (int i = 0; i < PER_THREAD; ++i) {
    if ((flags >> i) & 1) { sb[p++] = t * PER_THREAD + i; }
  }
  if (t == NTHREADS - 1) {
    counts[b] = base + cnt;   // total kept
    thetas[b] = theta;
  }
}

// ---------------------------------------------------------------------------
// Kernel 2: DIRECT-GLOBAL gather. No LDS, no barriers, no staging.
// One block per (b, c) row; 1D grid of B*C = 6144 blocks, 4 waves each.
// src indices are ascending, so a wave's 256 gathered dwords span a ~1.8x
// window of the 16 KB row -> reads stay cache-line-coalesced and the row is
// L1/L2 resident within the block. Tail waves (d0 >= cnt) skip all loads on
// a uniform branch. Pure streaming load->select->store, max occupancy,
// maximal outstanding requests.
// ---------------------------------------------------------------------------
__global__ __launch_bounds__(NTHREADS) void gather_kernel(
    const float* __restrict__ x,        // [B, C, L]
    const int*  __restrict__ src_idx,   // [B, L]
    const int*  __restrict__ counts,    // [B]
    const float* __restrict__ thetas,   // [B]
    float* __restrict__ out,            // [B, C, L]
    float* __restrict__ out_tail)       // 2 floats: keep_ratio, theta_mean
{
  const int bc = blockIdx.x;            // [0, B*C)
  const int b  = bc / C_;
  const int t  = threadIdx.x;

  // ---- folded finalize: block 0, wave 0 only ----
  if (bc == 0 && t < 64) {
    float cc = (t < B_) ? (float)counts[t] : 0.0f;
    float th = (t < B_) ? thetas[t]        : 0.0f;
    #pragma unroll
    for (int off = 32; off; off >>= 1) {
      cc += __shfl_down(cc, off, 64);
      th += __shfl_down(th, off, 64);
    }
    if (t == 0) {
      out_tail[0] = (cc / (float)B_) / (float)L_;  // keep_ratio
      out_tail[1] = th / (float)B_;                // theta_mean
    }
  }

  const size_t rowbase = (size_t)bc * L_;
  const float* xr  = x + rowbase;
  const int    cnt = counts[b];
  const int4*  s4b = (const int4*)(src_idx + (size_t)b * L_);
  f32x4*       o4  = (f32x4*)(out + rowbase);

  #pragma unroll
  for (int i = 0; i < 4; ++i) {
    const int j  = t + NTHREADS * i;    // float4 dest index in [0, 1024)
    const int d0 = j * 4;
    f32x4 r = {0.0f, 0.0f, 0.0f, 0.0f};
    if (d0 < cnt) {                     // uniform for all-tail waves
      const int4 s = s4b[j];
      // & (L_-1) keeps garbage indices (d >= cnt slots) in-row -> loads are
      // always safe; the selects below zero the dead lanes.
      r.x = xr[s.x & (L_ - 1)];
      r.y = (d0 + 1 < cnt) ? xr[s.y & (L_ - 1)] : 0.0f;
      r.z = (d0 + 2 < cnt) ? xr[s.z & (L_ - 1)] : 0.0f;
      r.w = (d0 + 3 < cnt) ? xr[s.w & (L_ - 1)] : 0.0f;
    }
    o4[j] = r;
  }
}

// ---------------------------------------------------------------------------
extern "C" void kernel_launch(void* const* d_in, const int* in_sizes, int n_in,
                              void* d_out, int out_size, void* d_ws, size_t ws_size,
                              hipStream_t stream) {
  const float* x     = (const float*)d_in[0];   // [32,192,64,64]
  const float* delta = (const float*)d_in[1];   // [32,1,64,64]
  float* out = (float*)d_out;                   // y (B*C*L) ++ keep_ratio ++ theta_mean

  // workspace layout (unchanged)
  int*   src_idx = (int*)d_ws;                                   // B*L ints = 512 KB
  int*   counts  = (int*)((char*)d_ws + (size_t)B_ * L_ * 4);    // 32 ints
  float* thetas  = (float*)((char*)d_ws + (size_t)B_ * L_ * 4 + 128);

  const size_t y_elems = (size_t)B_ * C_ * L_;  // 25,165,824
  float* out_tail = out + y_elems;

  stats_scan_kernel<<<B_, NTHREADS, 0, stream>>>(delta, src_idx, counts, thetas);
  gather_kernel<<<B_ * C_, NTHREADS, 0, stream>>>(x, src_idx, counts, thetas,
                                                  out, out_tail);
}